// Round 4
// baseline (498.455 us; speedup 1.0000x reference)
//
#include <hip/hip_runtime.h>
#include <hip/hip_bf16.h>

#define NN 50000
#define NE 600000
#define DD 128
#define RB 64            // rows per MFMA block (4 waves x 16 rows)
#define NSHARD_DIV 6250  // NN/8 node-range per XCD shard
#define GB ((NN + RB - 1) / RB)      // 782 MFMA blocks
#define EBQ ((NE + 1023) / 1024)     // 586 edge chunks (4 edges/thread)
#define SB ((NN + 1023) / 1024)      // 49 scan blocks
#define GQB (8 * ((NN + 31) / 32))   // 12504 gather blocks (8 planes x 1563)

typedef __bf16 bfrag __attribute__((ext_vector_type(8)));
typedef float  ffrag __attribute__((ext_vector_type(4)));
typedef unsigned uintv4 __attribute__((ext_vector_type(4)));   // native vec for nontemporal
typedef unsigned uintv2 __attribute__((ext_vector_type(2)));

union frag_cast { uintv4 u4; unsigned u[4]; bfrag b; };

__device__ __forceinline__ float bfbits2f(unsigned v) { return __uint_as_float(v << 16); }
__device__ __forceinline__ unsigned f2bfbits(float f) {
    unsigned u = __float_as_uint(f);
    return (u + 0x7FFFu + ((u >> 16) & 1u)) >> 16;   // RNE
}

__device__ __forceinline__ float ld_in(const void* p, int idx, int f32) {
    return f32 ? ((const float*)p)[idx]
               : bfbits2f(((const unsigned short*)p)[idx]);
}

__device__ __forceinline__ void ld_edge_nt(const int* adj, int e, int i64, int& s, int& d) {
    if (i64) {
        s = __builtin_nontemporal_load(&adj[4 * e]);
        d = __builtin_nontemporal_load(&adj[4 * e + 2]);
    } else {
        s = __builtin_nontemporal_load(&adj[2 * e]);
        d = __builtin_nontemporal_load(&adj[2 * e + 1]);
    }
}

// ---------------- prep: weight transpose + sniff + DEG zeroing ----------------
__global__ void k_prep(const unsigned* __restrict__ Ww, const unsigned* __restrict__ adjw,
                       const void* __restrict__ We, const void* __restrict__ Wu,
                       unsigned short* __restrict__ WeT, unsigned short* __restrict__ WuT,
                       int* __restrict__ flags, int* __restrict__ deg) {
    const int tid = threadIdx.x;
    if (blockIdx.x < DD) {
        __shared__ int scnt;
        if (tid == 0) scnt = 0;
        __syncthreads();
        int c = 0;
        for (int i = tid; i < 512; i += 256) {
            unsigned e = (Ww[i] >> 7) & 0xFFu;
            c += (e >= 0x60u && e <= 0x85u) ? 1 : 0;   // plausible low-half bf16?
        }
        atomicAdd(&scnt, c);
        __syncthreads();
        const int f32 = (scnt >= 256) ? 0 : 1;
        const int k = blockIdx.x;
        if (tid < DD) {
            WeT[tid * DD + k] = (unsigned short)f2bfbits(ld_in(We, k * DD + tid, f32));
        } else {
            int n = tid - DD;
            WuT[n * DD + k] = (unsigned short)f2bfbits(ld_in(Wu, k * DD + n, f32));
        }
        return;
    }
    for (int i = (blockIdx.x - DD) * 256 + tid; i < NN; i += 64 * 256) deg[i] = 0;
    if (blockIdx.x != DD) return;
    __shared__ int cnt[2];
    if (tid < 2) cnt[tid] = 0;
    __syncthreads();
    int c0 = 0, c1 = 0;
    for (int i = tid; i < 512; i += 256) {
        unsigned e = (Ww[i] >> 7) & 0xFFu;
        c0 += (e >= 0x60u && e <= 0x85u) ? 1 : 0;
        c1 += (adjw[2 * i + 1] == 0u) ? 1 : 0;          // int64 zero high words?
    }
    atomicAdd(&cnt[0], c0);
    atomicAdd(&cnt[1], c1);
    __syncthreads();
    if (tid == 0) {
        flags[0] = (cnt[0] >= 256) ? 0 : 1;   // fp32 inputs?
        flags[1] = (cnt[1] >= 256) ? 1 : 0;   // int64 adjacency?
    }
}

// ---------------- W staging: fragment-major LDS, INVERSE permutation ----------------
// LDS dst is tid-contiguous (conflict-free ds_write_b128: 2 lanes/bank = free);
// the permuted GLOBAL read is L2-hot (32 KB reused by every block). Round-3's
// forward version scattered the LDS writes -> 1.4M residual bank conflicts.
// Unit d holds W^T row (ct*16+m), cols ks*32+quad*8..+8 with
// d = ((ct*4+ks)*4+quad)*16 + m  <=>  src unit = (ct*16+m)*16 + (ks*4+quad).
__device__ __forceinline__ void stage_w(const uintv4* __restrict__ WTg, uintv4* sW, int tid) {
#pragma unroll
    for (int k = 0; k < 8; k++) {
        int d = k * 256 + tid;
        int m = d & 15, rest = d >> 4;
        int quad = rest & 3, ks = (rest >> 2) & 3, ct = rest >> 4;
        sW[d] = WTg[(ct * 16 + m) * 16 + (ks * 4 + quad)];
    }
}

// ---------------- MFMA core: A from registers, B fragment-major from LDS ----------
__device__ __forceinline__ void mfma_rows(const bfrag af[4], const bfrag* sW,
                                          int m, int quad, ffrag acc[8]) {
#pragma unroll
    for (int ks = 0; ks < 4; ks++) {
#pragma unroll
        for (int ct = 0; ct < 8; ct++) {
            bfrag bf_ = sW[((ct * 4 + ks) * 4 + quad) * 16 + m];
            acc[ct] = __builtin_amdgcn_mfma_f32_16x16x32_bf16(af[ks], bf_, acc[ct], 0, 0, 0);
        }
    }
}

// ---------------- fused: emb GEMM (blocks < GB) || degree+slot atomics (rest) ------
// h0 written PLANE-BLOCKED: H[plane][node][16 cols], plane = col>>4. Each 1.6 MB
// plane then fits one XCD's 4 MB L2 during the column-sharded gather.
__launch_bounds__(256, 5)
__global__ void k_main1(const void* __restrict__ Xp, const unsigned short* __restrict__ WTg,
                        const void* __restrict__ Bp, unsigned short* __restrict__ Hout,
                        const int* __restrict__ flags, const int* __restrict__ adj,
                        int* __restrict__ deg, uintv2* __restrict__ edg) {
    __shared__ __align__(16) unsigned short sWT[DD * DD];  // 32 KB
    const int tid = threadIdx.x;
    if (blockIdx.x >= GB) {
        // -------- edge path: degree count with returning atomics --------
        const int bb = blockIdx.x - GB;
        const int i64 = flags[1];
#pragma unroll
        for (int k = 0; k < 4; k++) {
            const int e = bb * 1024 + k * 256 + tid;
            if (e < NE) {
                int s, d;
                ld_edge_nt(adj, e, i64, s, d);
                uintv2 out;
                if ((unsigned)s < NN && (unsigned)d < NN) {
                    int ks = atomicAdd(&deg[s], 1);
                    int kd = atomicAdd(&deg[d], 1);
                    out[0] = (unsigned)s | ((unsigned)d << 16);
                    out[1] = (unsigned)ks | ((unsigned)kd << 16);  // max deg ~60 << 65536
                } else {
                    out[0] = 0xFFFFFFFFu;  // sentinel: skip in fill
                    out[1] = 0;
                }
                __builtin_nontemporal_store(out, &edg[e]);
            }
        }
        return;
    }
    // -------- emb path: h0 = relu(X @ W_emb + b) -> bf16 planes --------
    const int wave = tid >> 6;
    const int lane = tid & 63;
    const int f32  = flags[0];
    const int m    = lane & 15;
    const int quad = lane >> 4;
    const int rowbase = blockIdx.x * RB + wave * 16;
    const int row  = rowbase + m;
    const int rc   = (row < NN) ? row : (NN - 1);   // clamp for load; stores guarded

    stage_w((const uintv4*)WTg, (uintv4*)sWT, tid);

    bfrag af[4];
    if (f32) {
        const float4* Xf = (const float4*)Xp;
#pragma unroll
        for (int ks = 0; ks < 4; ks++) {
            const int k0 = ks * 32 + quad * 8;
            float4 a0 = Xf[rc * 32 + (k0 >> 2)];
            float4 a1 = Xf[rc * 32 + (k0 >> 2) + 1];
            frag_cast fc;
            fc.u[0] = f2bfbits(a0.x) | (f2bfbits(a0.y) << 16);
            fc.u[1] = f2bfbits(a0.z) | (f2bfbits(a0.w) << 16);
            fc.u[2] = f2bfbits(a1.x) | (f2bfbits(a1.y) << 16);
            fc.u[3] = f2bfbits(a1.z) | (f2bfbits(a1.w) << 16);
            af[ks] = fc.b;
        }
    } else {
        const uintv4* Xv = (const uintv4*)Xp;
#pragma unroll
        for (int ks = 0; ks < 4; ks++) {
            const int k0 = ks * 32 + quad * 8;
            frag_cast fc;
            fc.u4 = Xv[rc * 16 + (k0 >> 3)];
            af[ks] = fc.b;
        }
    }
    __syncthreads();

    ffrag acc[8];
#pragma unroll
    for (int i = 0; i < 8; i++) acc[i] = (ffrag)(0.0f);
    mfma_rows(af, (const bfrag*)sWT, m, quad, acc);

#pragma unroll
    for (int ct = 0; ct < 8; ct++) {
        int col = ct * 16 + m;
        float bb = ld_in(Bp, col, f32);
#pragma unroll
        for (int reg = 0; reg < 4; reg++) {
            int orow = rowbase + quad * 4 + reg;
            if (orow < NN) {
                float z = fmaxf(acc[ct][reg] + bb, 0.0f);
                Hout[ct * (NN * 16) + orow * 16 + m] = (unsigned short)f2bfbits(z);
            }
        }
    }
}

// ---------------- hierarchical scan (wave-shuffle, 2 barriers) ----------------
__global__ void k_scan1(const int* __restrict__ deg, int* __restrict__ rows,
                        int* __restrict__ sums) {
    __shared__ int wsum[16];
    __shared__ int woff[16];
    const int tid  = threadIdx.x;
    const int wid  = tid >> 6;
    const int lane = tid & 63;
    const int i = blockIdx.x * 1024 + tid;
    int x = (i < NN) ? deg[i] : 0;
#pragma unroll
    for (int off = 1; off < 64; off <<= 1) {
        int y = __shfl_up(x, off, 64);
        if (lane >= off) x += y;
    }
    if (lane == 63) wsum[wid] = x;
    __syncthreads();
    if (wid == 0) {
        int s  = (lane < 16) ? wsum[lane] : 0;
        int xs = s;
#pragma unroll
        for (int off = 1; off < 16; off <<= 1) {
            int y = __shfl_up(xs, off, 64);
            if (lane >= off) xs += y;
        }
        if (lane < 16) woff[lane] = xs - s;
        if (lane == 15) sums[blockIdx.x] = xs;
    }
    __syncthreads();
    if (i < NN) rows[i + 1] = x + woff[wid];
}

__global__ void k_scan2(int* __restrict__ sums, int nb) {
    int t = threadIdx.x;                 // one wave of 64
    int v = (t < nb) ? sums[t] : 0;
    int x = v;
    for (int off = 1; off < 64; off <<= 1) {
        int y = __shfl_up(x, off, 64);
        if (t >= off) x += y;
    }
    if (t < nb) sums[t] = x - v;         // exclusive
}

__global__ void k_scan3(const int* __restrict__ sums, int* __restrict__ rows) {
    int i = blockIdx.x * 1024 + threadIdx.x;
    if (i < NN) {
        rows[i + 1] += sums[blockIdx.x];
        if (i == 0) rows[0] = 0;
    }
}

// ---------------- atomic-free XCD-sharded fill: slot = rows[s] + precomputed ks ----
__launch_bounds__(256)
__global__ void k_fill2(const uintv2* __restrict__ edg, const int* __restrict__ rows,
                        unsigned short* __restrict__ nbr) {
    const int shard = blockIdx.x & 7;
    const int bb = blockIdx.x >> 3;
#pragma unroll
    for (int k = 0; k < 4; k++) {
        const int e = bb * 1024 + k * 256 + threadIdx.x;
        if (e >= NE) continue;
        uintv2 v = __builtin_nontemporal_load(&edg[e]);
        if (v[0] == 0xFFFFFFFFu) continue;
        const int s = v[0] & 0xFFFFu, d = v[0] >> 16;
        if (s / NSHARD_DIV == shard) nbr[rows[s] + (v[1] & 0xFFFFu)] = (unsigned short)d;
        if (d / NSHARD_DIV == shard) nbr[rows[d] + (v[1] >> 16)]    = (unsigned short)s;
    }
}

// ---------------- column-sharded gather: plane (blockIdx&7) -> one XCD's L2 --------
// H input is plane-blocked [8][NN][16cols]; each XCD's working set = 1.6 MB plane
// (fits 4 MB L2) PROVIDED the 2.4 MB/pass nbr stream doesn't evict it: nbr loads
// are NONTEMPORAL (evict-first) so only plane+rows stay resident.
__launch_bounds__(256)
__global__ void k_gath3(const unsigned* __restrict__ Hp, const int* __restrict__ rows,
                        const unsigned short* __restrict__ nbr,
                        unsigned* __restrict__ XB32) {
    const int shard = blockIdx.x & 7;
    const int node  = (blockIdx.x >> 3) * 32 + (threadIdx.x >> 3);
    const int cs    = threadIdx.x & 7;
    const int nc    = (node < NN) ? node : (NN - 1);
    const unsigned* P = Hp + (size_t)shard * (NN * 8);
    const int st = rows[nc], en = rows[nc + 1];
    unsigned sv = P[nc * 8 + cs];                      // self term (plane-resident)
    float ax = bfbits2f(sv & 0xFFFFu);
    float ay = bfbits2f(sv >> 16);
    int j = st;
    for (; j + 8 <= en; j += 8) {                      // deep unroll: 16 loads in flight
        int n[8];
#pragma unroll
        for (int t = 0; t < 8; t++) n[t] = __builtin_nontemporal_load(&nbr[j + t]);
        unsigned v[8];
#pragma unroll
        for (int t = 0; t < 8; t++) v[t] = P[n[t] * 8 + cs];
#pragma unroll
        for (int t = 0; t < 8; t++) {
            ax += bfbits2f(v[t] & 0xFFFFu);
            ay += bfbits2f(v[t] >> 16);
        }
    }
    for (; j + 2 <= en; j += 2) {
        int n0 = __builtin_nontemporal_load(&nbr[j]);
        int n1 = __builtin_nontemporal_load(&nbr[j + 1]);
        unsigned v0 = P[n0 * 8 + cs], v1 = P[n1 * 8 + cs];
        ax += bfbits2f(v0 & 0xFFFFu) + bfbits2f(v1 & 0xFFFFu);
        ay += bfbits2f(v0 >> 16) + bfbits2f(v1 >> 16);
    }
    for (; j < en; ++j) {
        unsigned v = P[(int)__builtin_nontemporal_load(&nbr[j]) * 8 + cs];
        ax += bfbits2f(v & 0xFFFFu);
        ay += bfbits2f(v >> 16);
    }
    const float inv = 1.0f / (float)(en - st + 1);
    if (node < NN) {
        unsigned pk = f2bfbits(ax * inv) | (f2bfbits(ay * inv) << 16);
        __builtin_nontemporal_store(pk, &XB32[node * 64 + shard * 8 + cs]);  // keep L2 for H
    }
}

// ---------------- GEMM 2: h_new = sigmoid(XB @ W_upd + b) ----------------
// !last: write plane-blocked bf16 (feeds next gather). last: row-major to d_out.
__launch_bounds__(256, 5)
__global__ void k_gemmB(const unsigned short* __restrict__ XB,
                        const unsigned short* __restrict__ WTg, const void* __restrict__ Bp,
                        unsigned short* __restrict__ HoutBf, float* __restrict__ HoutF,
                        const int* __restrict__ flags, int last) {
    __shared__ __align__(16) unsigned short sWT[DD * DD];  // 32 KB
    const int tid  = threadIdx.x;
    const int wave = tid >> 6;
    const int lane = tid & 63;
    const int f32  = flags[0];
    const int m    = lane & 15;
    const int quad = lane >> 4;
    const int rowbase = blockIdx.x * RB + wave * 16;
    const int row  = rowbase + m;

    stage_w((const uintv4*)WTg, (uintv4*)sWT, tid);

    bfrag af[4];
    const uintv4* Xv = (const uintv4*)XB;
#pragma unroll
    for (int ks = 0; ks < 4; ks++) {
        const int k0 = ks * 32 + quad * 8;
        frag_cast fc;
        fc.u4 = __builtin_nontemporal_load(&Xv[row * 16 + (k0 >> 3)]);  // single-use stream
        af[ks] = fc.b;
    }
    __syncthreads();

    ffrag acc[8];
#pragma unroll
    for (int i = 0; i < 8; i++) acc[i] = (ffrag)(0.0f);
    mfma_rows(af, (const bfrag*)sWT, m, quad, acc);

#pragma unroll
    for (int ct = 0; ct < 8; ct++) {
        int col = ct * 16 + m;
        float bb = ld_in(Bp, col, f32);
#pragma unroll
        for (int reg = 0; reg < 4; reg++) {
            int orow = rowbase + quad * 4 + reg;
            if (orow < NN) {
                float s = 1.0f / (1.0f + __expf(-(acc[ct][reg] + bb)));
                if (!last) {
                    HoutBf[ct * (NN * 16) + orow * 16 + m] = (unsigned short)f2bfbits(s);
                } else if (f32) {
                    HoutF[orow * DD + col] = s;
                } else {
                    ((unsigned short*)HoutF)[orow * DD + col] = (unsigned short)f2bfbits(s);
                }
            }
        }
    }
}

extern "C" void kernel_launch(void* const* d_in, const int* in_sizes, int n_in,
                              void* d_out, int out_size, void* d_ws, size_t ws_size,
                              hipStream_t stream) {
    const void* X  = d_in[0];
    const void* We = d_in[1];
    const void* be = d_in[2];
    const void* Wu = d_in[3];
    const void* bu = d_in[4];
    const int* adj = (const int*)d_in[5];

    // ws: FLAGS | ROWS | SUMS | NBR(2.4M) | WeT | WuT | HW(12.8M + 16K slack)
    // HW overlays EDG2(4.8M) + DEG(200K): both dead after fill2/scan1, before it0
    // writes HW. Total ~15.5 MB.
    char* p = (char*)d_ws;
    int* FLAGS = (int*)p;                       p += 256;
    int* ROWS  = (int*)p;                       p += ((NN + 1) * 4 + 252) / 256 * 256;
    int* SUMS  = (int*)p;                       p += 256;
    unsigned short* NBR = (unsigned short*)p;   p += (size_t)2 * NE * 2;
    unsigned short* WeT = (unsigned short*)p;   p += DD * DD * 2;
    unsigned short* WuT = (unsigned short*)p;   p += DD * DD * 2;
    unsigned short* HW  = (unsigned short*)p;   // 12.8 MB + slack (gemmB over-read)
    uintv2* EDG2 = (uintv2*)p;                  // overlays HW[0 .. 4.8M)
    int* DEG = (int*)(p + (size_t)NE * 8);      // overlays HW[4.8M .. 5.0M)

    // h planes live in d_out's upper half (bytes 12.8M..25.6M); dead before the
    // final row-major f32 write (gather consumes them first, stream-ordered).
    unsigned short* HA = (unsigned short*)d_out + (size_t)NN * DD;

    k_prep<<<DD + 64, 256, 0, stream>>>((const unsigned*)We, (const unsigned*)adj,
                                        We, Wu, WeT, WuT, FLAGS, DEG);
    k_main1<<<GB + EBQ, 256, 0, stream>>>(X, WeT, be, HA, FLAGS, adj, DEG, EDG2);
    k_scan1<<<SB, 1024, 0, stream>>>(DEG, ROWS, SUMS);
    k_scan2<<<1, 64, 0, stream>>>(SUMS, SB);
    k_scan3<<<SB, 1024, 0, stream>>>(SUMS, ROWS);
    k_fill2<<<8 * EBQ, 256, 0, stream>>>(EDG2, ROWS, NBR);

    for (int it = 0; it < 3; ++it) {
        int last = (it == 2);
        k_gath3<<<GQB, 256, 0, stream>>>((const unsigned*)HA, ROWS, NBR, (unsigned*)HW);
        k_gemmB<<<GB, 256, 0, stream>>>(HW, WuT, bu, HA, (float*)d_out, FLAGS, last);
    }
}

// Round 5
// 392.683 us; speedup vs baseline: 1.2694x; 1.2694x over previous
//
#include <hip/hip_runtime.h>
#include <hip/hip_bf16.h>

#define NN 50000
#define NE 600000
#define DD 128
#define RB 64            // rows per MFMA block (4 waves x 16 rows)
#define NSHARD_DIV 6250  // NN/8 node-range per XCD shard
#define GB ((NN + RB - 1) / RB)      // 782 MFMA blocks
#define EBQ ((NE + 1023) / 1024)     // 586 edge chunks (4 edges/thread)
#define SB ((NN + 1023) / 1024)      // 49 scan blocks
#define GQB (8 * ((NN + 31) / 32))   // 12504 gather blocks (8 planes x 1563)

typedef __bf16 bfrag __attribute__((ext_vector_type(8)));
typedef float  ffrag __attribute__((ext_vector_type(4)));
typedef unsigned uintv4 __attribute__((ext_vector_type(4)));   // native vec for nontemporal
typedef unsigned uintv2 __attribute__((ext_vector_type(2)));

union frag_cast { uintv4 u4; unsigned u[4]; bfrag b; };

__device__ __forceinline__ float bfbits2f(unsigned v) { return __uint_as_float(v << 16); }
__device__ __forceinline__ unsigned f2bfbits(float f) {
    unsigned u = __float_as_uint(f);
    return (u + 0x7FFFu + ((u >> 16) & 1u)) >> 16;   // RNE
}

__device__ __forceinline__ float ld_in(const void* p, int idx, int f32) {
    return f32 ? ((const float*)p)[idx]
               : bfbits2f(((const unsigned short*)p)[idx]);
}

__device__ __forceinline__ void ld_edge_nt(const int* adj, int e, int i64, int& s, int& d) {
    if (i64) {
        s = __builtin_nontemporal_load(&adj[4 * e]);
        d = __builtin_nontemporal_load(&adj[4 * e + 2]);
    } else {
        s = __builtin_nontemporal_load(&adj[2 * e]);
        d = __builtin_nontemporal_load(&adj[2 * e + 1]);
    }
}

// ---------------- prep: weight transpose + sniff + DEG zeroing ----------------
__global__ void k_prep(const unsigned* __restrict__ Ww, const unsigned* __restrict__ adjw,
                       const void* __restrict__ We, const void* __restrict__ Wu,
                       unsigned short* __restrict__ WeT, unsigned short* __restrict__ WuT,
                       int* __restrict__ flags, int* __restrict__ deg) {
    const int tid = threadIdx.x;
    if (blockIdx.x < DD) {
        __shared__ int scnt;
        if (tid == 0) scnt = 0;
        __syncthreads();
        int c = 0;
        for (int i = tid; i < 512; i += 256) {
            unsigned e = (Ww[i] >> 7) & 0xFFu;
            c += (e >= 0x60u && e <= 0x85u) ? 1 : 0;   // plausible low-half bf16?
        }
        atomicAdd(&scnt, c);
        __syncthreads();
        const int f32 = (scnt >= 256) ? 0 : 1;
        const int k = blockIdx.x;
        if (tid < DD) {
            WeT[tid * DD + k] = (unsigned short)f2bfbits(ld_in(We, k * DD + tid, f32));
        } else {
            int n = tid - DD;
            WuT[n * DD + k] = (unsigned short)f2bfbits(ld_in(Wu, k * DD + n, f32));
        }
        return;
    }
    for (int i = (blockIdx.x - DD) * 256 + tid; i < NN; i += 64 * 256) deg[i] = 0;
    if (blockIdx.x != DD) return;
    __shared__ int cnt[2];
    if (tid < 2) cnt[tid] = 0;
    __syncthreads();
    int c0 = 0, c1 = 0;
    for (int i = tid; i < 512; i += 256) {
        unsigned e = (Ww[i] >> 7) & 0xFFu;
        c0 += (e >= 0x60u && e <= 0x85u) ? 1 : 0;
        c1 += (adjw[2 * i + 1] == 0u) ? 1 : 0;          // int64 zero high words?
    }
    atomicAdd(&cnt[0], c0);
    atomicAdd(&cnt[1], c1);
    __syncthreads();
    if (tid == 0) {
        flags[0] = (cnt[0] >= 256) ? 0 : 1;   // fp32 inputs?
        flags[1] = (cnt[1] >= 256) ? 1 : 0;   // int64 adjacency?
    }
}

// ---------------- W staging: fragment-major LDS, INVERSE permutation ----------------
// LDS dst is tid-contiguous (canonical conflict-free ds_write_b128); the permuted
// GLOBAL read is L2-hot (32 KB reused by every block).
__device__ __forceinline__ void stage_w(const uintv4* __restrict__ WTg, uintv4* sW, int tid) {
#pragma unroll
    for (int k = 0; k < 8; k++) {
        int d = k * 256 + tid;
        int m = d & 15, rest = d >> 4;
        int quad = rest & 3, ks = (rest >> 2) & 3, ct = rest >> 4;
        sW[d] = WTg[(ct * 16 + m) * 16 + (ks * 4 + quad)];
    }
}

// ---------------- MFMA core: A from registers, B fragment-major from LDS ----------
__device__ __forceinline__ void mfma_rows(const bfrag af[4], const bfrag* sW,
                                          int m, int quad, ffrag acc[8]) {
#pragma unroll
    for (int ks = 0; ks < 4; ks++) {
#pragma unroll
        for (int ct = 0; ct < 8; ct++) {
            bfrag bf_ = sW[((ct * 4 + ks) * 4 + quad) * 16 + m];
            acc[ct] = __builtin_amdgcn_mfma_f32_16x16x32_bf16(af[ks], bf_, acc[ct], 0, 0, 0);
        }
    }
}

// ---------------- fused: emb GEMM (blocks < GB) || degree+slot atomics (rest) ------
// h0 written PLANE-BLOCKED: H[plane][node][16 cols], plane = col>>4. Each 1.6 MB
// plane then fits one XCD's 4 MB L2 during the column-sharded gather.
__launch_bounds__(256, 5)
__global__ void k_main1(const void* __restrict__ Xp, const unsigned short* __restrict__ WTg,
                        const void* __restrict__ Bp, unsigned short* __restrict__ Hout,
                        const int* __restrict__ flags, const int* __restrict__ adj,
                        int* __restrict__ deg, uintv2* __restrict__ edg) {
    __shared__ __align__(16) unsigned short sWT[DD * DD];  // 32 KB
    const int tid = threadIdx.x;
    if (blockIdx.x >= GB) {
        // -------- edge path: degree count with returning atomics --------
        const int bb = blockIdx.x - GB;
        const int i64 = flags[1];
#pragma unroll
        for (int k = 0; k < 4; k++) {
            const int e = bb * 1024 + k * 256 + tid;
            if (e < NE) {
                int s, d;
                ld_edge_nt(adj, e, i64, s, d);
                uintv2 out;
                if ((unsigned)s < NN && (unsigned)d < NN) {
                    int ks = atomicAdd(&deg[s], 1);
                    int kd = atomicAdd(&deg[d], 1);
                    out[0] = (unsigned)s | ((unsigned)d << 16);
                    out[1] = (unsigned)ks | ((unsigned)kd << 16);  // max deg ~60 << 65536
                } else {
                    out[0] = 0xFFFFFFFFu;  // sentinel: skip in fill
                    out[1] = 0;
                }
                __builtin_nontemporal_store(out, &edg[e]);
            }
        }
        return;
    }
    // -------- emb path: h0 = relu(X @ W_emb + b) -> bf16 planes --------
    const int wave = tid >> 6;
    const int lane = tid & 63;
    const int f32  = flags[0];
    const int m    = lane & 15;
    const int quad = lane >> 4;
    const int rowbase = blockIdx.x * RB + wave * 16;
    const int row  = rowbase + m;
    const int rc   = (row < NN) ? row : (NN - 1);   // clamp for load; stores guarded

    stage_w((const uintv4*)WTg, (uintv4*)sWT, tid);

    bfrag af[4];
    if (f32) {
        const float4* Xf = (const float4*)Xp;
#pragma unroll
        for (int ks = 0; ks < 4; ks++) {
            const int k0 = ks * 32 + quad * 8;
            float4 a0 = Xf[rc * 32 + (k0 >> 2)];
            float4 a1 = Xf[rc * 32 + (k0 >> 2) + 1];
            frag_cast fc;
            fc.u[0] = f2bfbits(a0.x) | (f2bfbits(a0.y) << 16);
            fc.u[1] = f2bfbits(a0.z) | (f2bfbits(a0.w) << 16);
            fc.u[2] = f2bfbits(a1.x) | (f2bfbits(a1.y) << 16);
            fc.u[3] = f2bfbits(a1.z) | (f2bfbits(a1.w) << 16);
            af[ks] = fc.b;
        }
    } else {
        const uintv4* Xv = (const uintv4*)Xp;
#pragma unroll
        for (int ks = 0; ks < 4; ks++) {
            const int k0 = ks * 32 + quad * 8;
            frag_cast fc;
            fc.u4 = Xv[rc * 16 + (k0 >> 3)];
            af[ks] = fc.b;
        }
    }
    __syncthreads();

    ffrag acc[8];
#pragma unroll
    for (int i = 0; i < 8; i++) acc[i] = (ffrag)(0.0f);
    mfma_rows(af, (const bfrag*)sWT, m, quad, acc);

#pragma unroll
    for (int ct = 0; ct < 8; ct++) {
        int col = ct * 16 + m;
        float bb = ld_in(Bp, col, f32);
#pragma unroll
        for (int reg = 0; reg < 4; reg++) {
            int orow = rowbase + quad * 4 + reg;
            if (orow < NN) {
                float z = fmaxf(acc[ct][reg] + bb, 0.0f);
                Hout[ct * (NN * 16) + orow * 16 + m] = (unsigned short)f2bfbits(z);
            }
        }
    }
}

// ---------------- hierarchical scan (wave-shuffle, 2 barriers) ----------------
__global__ void k_scan1(const int* __restrict__ deg, int* __restrict__ rows,
                        int* __restrict__ sums) {
    __shared__ int wsum[16];
    __shared__ int woff[16];
    const int tid  = threadIdx.x;
    const int wid  = tid >> 6;
    const int lane = tid & 63;
    const int i = blockIdx.x * 1024 + tid;
    int x = (i < NN) ? deg[i] : 0;
#pragma unroll
    for (int off = 1; off < 64; off <<= 1) {
        int y = __shfl_up(x, off, 64);
        if (lane >= off) x += y;
    }
    if (lane == 63) wsum[wid] = x;
    __syncthreads();
    if (wid == 0) {
        int s  = (lane < 16) ? wsum[lane] : 0;
        int xs = s;
#pragma unroll
        for (int off = 1; off < 16; off <<= 1) {
            int y = __shfl_up(xs, off, 64);
            if (lane >= off) xs += y;
        }
        if (lane < 16) woff[lane] = xs - s;
        if (lane == 15) sums[blockIdx.x] = xs;
    }
    __syncthreads();
    if (i < NN) rows[i + 1] = x + woff[wid];
}

__global__ void k_scan2(int* __restrict__ sums, int nb) {
    int t = threadIdx.x;                 // one wave of 64
    int v = (t < nb) ? sums[t] : 0;
    int x = v;
    for (int off = 1; off < 64; off <<= 1) {
        int y = __shfl_up(x, off, 64);
        if (t >= off) x += y;
    }
    if (t < nb) sums[t] = x - v;         // exclusive
}

__global__ void k_scan3(const int* __restrict__ sums, int* __restrict__ rows) {
    int i = blockIdx.x * 1024 + threadIdx.x;
    if (i < NN) {
        rows[i + 1] += sums[blockIdx.x];
        if (i == 0) rows[0] = 0;
    }
}

// ---------------- atomic-free XCD-sharded fill: slot = rows[s] + precomputed ks ----
__launch_bounds__(256)
__global__ void k_fill2(const uintv2* __restrict__ edg, const int* __restrict__ rows,
                        unsigned short* __restrict__ nbr) {
    const int shard = blockIdx.x & 7;
    const int bb = blockIdx.x >> 3;
#pragma unroll
    for (int k = 0; k < 4; k++) {
        const int e = bb * 1024 + k * 256 + threadIdx.x;
        if (e >= NE) continue;
        uintv2 v = __builtin_nontemporal_load(&edg[e]);
        if (v[0] == 0xFFFFFFFFu) continue;
        const int s = v[0] & 0xFFFFu, d = v[0] >> 16;
        if (s / NSHARD_DIV == shard) nbr[rows[s] + (v[1] & 0xFFFFu)] = (unsigned short)d;
        if (d / NSHARD_DIV == shard) nbr[rows[d] + (v[1] >> 16)]    = (unsigned short)s;
    }
}

// ---------------- column-sharded gather: plane (blockIdx&7) -> one XCD's L2 --------
// H plane-blocked [8][NN][16cols]; 1.6 MB plane stays resident in the XCD's 4 MB L2
// (round-4 FETCH confirmed). nbr indices fetched COOPERATIVELY: lane cs loads
// nbr[j+cs] once per 8-block (1 sector/group instead of 8 separate scalar-load
// instructions), distributed via __shfl (LDS pipe, off the TA critical path).
// NO nontemporal on nbr (round-4: nt killed line reuse, +26 us/gather).
__launch_bounds__(256)
__global__ void k_gath3(const unsigned* __restrict__ Hp, const int* __restrict__ rows,
                        const unsigned short* __restrict__ nbr,
                        unsigned* __restrict__ XB32) {
    const int shard = blockIdx.x & 7;
    const int lane  = threadIdx.x & 63;
    const int cs    = lane & 7;
    const int gbase = lane & 56;                       // 8-lane group base in wave
    const int node  = (blockIdx.x >> 3) * 32 + (threadIdx.x >> 3);
    const int nc    = (node < NN) ? node : (NN - 1);
    const unsigned* P = Hp + (size_t)shard * (NN * 8);
    const int st = rows[nc], en = rows[nc + 1];
    unsigned sv = P[nc * 8 + cs];                      // self term (plane-resident)
    float ax = bfbits2f(sv & 0xFFFFu);
    float ay = bfbits2f(sv >> 16);
    int j = st;
    if (j + 8 <= en) {
        int myn = (int)nbr[j + cs];                    // coop: group's next 8 indices
        for (; j + 8 <= en; j += 8) {
            int nx = (int)nbr[j + 8 + cs];             // prefetch next block
                                                       // (over-read <=30B lands in WeT: ws-safe)
            unsigned v[8];
#pragma unroll
            for (int t = 0; t < 8; t++) {
                int n = __shfl(myn, gbase + t, 64);    // broadcast within 8-lane group
                v[t] = P[n * 8 + cs];
            }
#pragma unroll
            for (int t = 0; t < 8; t++) {
                ax += bfbits2f(v[t] & 0xFFFFu);
                ay += bfbits2f(v[t] >> 16);
            }
            myn = nx;
        }
    }
    for (; j < en; ++j) {
        unsigned v = P[(int)nbr[j] * 8 + cs];
        ax += bfbits2f(v & 0xFFFFu);
        ay += bfbits2f(v >> 16);
    }
    const float inv = 1.0f / (float)(en - st + 1);
    if (node < NN) {
        unsigned pk = f2bfbits(ax * inv) | (f2bfbits(ay * inv) << 16);
        __builtin_nontemporal_store(pk, &XB32[node * 64 + shard * 8 + cs]);  // keep L2 for H
    }
}

// ---------------- GEMM 2: h_new = sigmoid(XB @ W_upd + b) ----------------
// !last: write plane-blocked bf16 (feeds next gather). last: row-major to d_out.
__launch_bounds__(256, 5)
__global__ void k_gemmB(const unsigned short* __restrict__ XB,
                        const unsigned short* __restrict__ WTg, const void* __restrict__ Bp,
                        unsigned short* __restrict__ HoutBf, float* __restrict__ HoutF,
                        const int* __restrict__ flags, int last) {
    __shared__ __align__(16) unsigned short sWT[DD * DD];  // 32 KB
    const int tid  = threadIdx.x;
    const int wave = tid >> 6;
    const int lane = tid & 63;
    const int f32  = flags[0];
    const int m    = lane & 15;
    const int quad = lane >> 4;
    const int rowbase = blockIdx.x * RB + wave * 16;
    const int row  = rowbase + m;

    stage_w((const uintv4*)WTg, (uintv4*)sWT, tid);

    bfrag af[4];
    const uintv4* Xv = (const uintv4*)XB;
#pragma unroll
    for (int ks = 0; ks < 4; ks++) {
        const int k0 = ks * 32 + quad * 8;
        frag_cast fc;
        fc.u4 = __builtin_nontemporal_load(&Xv[row * 16 + (k0 >> 3)]);  // single-use stream
        af[ks] = fc.b;
    }
    __syncthreads();

    ffrag acc[8];
#pragma unroll
    for (int i = 0; i < 8; i++) acc[i] = (ffrag)(0.0f);
    mfma_rows(af, (const bfrag*)sWT, m, quad, acc);

#pragma unroll
    for (int ct = 0; ct < 8; ct++) {
        int col = ct * 16 + m;
        float bb = ld_in(Bp, col, f32);
#pragma unroll
        for (int reg = 0; reg < 4; reg++) {
            int orow = rowbase + quad * 4 + reg;
            if (orow < NN) {
                float s = 1.0f / (1.0f + __expf(-(acc[ct][reg] + bb)));
                if (!last) {
                    HoutBf[ct * (NN * 16) + orow * 16 + m] = (unsigned short)f2bfbits(s);
                } else if (f32) {
                    HoutF[orow * DD + col] = s;
                } else {
                    ((unsigned short*)HoutF)[orow * DD + col] = (unsigned short)f2bfbits(s);
                }
            }
        }
    }
}

extern "C" void kernel_launch(void* const* d_in, const int* in_sizes, int n_in,
                              void* d_out, int out_size, void* d_ws, size_t ws_size,
                              hipStream_t stream) {
    const void* X  = d_in[0];
    const void* We = d_in[1];
    const void* be = d_in[2];
    const void* Wu = d_in[3];
    const void* bu = d_in[4];
    const int* adj = (const int*)d_in[5];

    // ws: FLAGS | ROWS | SUMS | NBR(2.4M) | WeT | WuT | HW(12.8M + 16K slack)
    // HW overlays EDG2(4.8M) + DEG(200K): both dead after fill2/scan1, before it0
    // writes HW. Total ~15.5 MB.
    char* p = (char*)d_ws;
    int* FLAGS = (int*)p;                       p += 256;
    int* ROWS  = (int*)p;                       p += ((NN + 1) * 4 + 252) / 256 * 256;
    int* SUMS  = (int*)p;                       p += 256;
    unsigned short* NBR = (unsigned short*)p;   p += (size_t)2 * NE * 2;
    unsigned short* WeT = (unsigned short*)p;   p += DD * DD * 2;
    unsigned short* WuT = (unsigned short*)p;   p += DD * DD * 2;
    unsigned short* HW  = (unsigned short*)p;   // 12.8 MB + slack (gemmB over-read)
    uintv2* EDG2 = (uintv2*)p;                  // overlays HW[0 .. 4.8M)
    int* DEG = (int*)(p + (size_t)NE * 8);      // overlays HW[4.8M .. 5.0M)

    // h planes live in d_out's upper half (bytes 12.8M..25.6M); dead before the
    // final row-major f32 write (gather consumes them first, stream-ordered).
    unsigned short* HA = (unsigned short*)d_out + (size_t)NN * DD;

    k_prep<<<DD + 64, 256, 0, stream>>>((const unsigned*)We, (const unsigned*)adj,
                                        We, Wu, WeT, WuT, FLAGS, DEG);
    k_main1<<<GB + EBQ, 256, 0, stream>>>(X, WeT, be, HA, FLAGS, adj, DEG, EDG2);
    k_scan1<<<SB, 1024, 0, stream>>>(DEG, ROWS, SUMS);
    k_scan2<<<1, 64, 0, stream>>>(SUMS, SB);
    k_scan3<<<SB, 1024, 0, stream>>>(SUMS, ROWS);
    k_fill2<<<8 * EBQ, 256, 0, stream>>>(EDG2, ROWS, NBR);

    for (int it = 0; it < 3; ++it) {
        int last = (it == 2);
        k_gath3<<<GQB, 256, 0, stream>>>((const unsigned*)HA, ROWS, NBR, (unsigned*)HW);
        k_gemmB<<<GB, 256, 0, stream>>>(HW, WuT, bu, HA, (float*)d_out, FLAGS, last);
    }
}

// Round 6
// 358.910 us; speedup vs baseline: 1.3888x; 1.0941x over previous
//
#include <hip/hip_runtime.h>
#include <hip/hip_bf16.h>

#define NN 50000
#define NE 600000
#define DD 128
#define RB 64            // rows per MFMA block (4 waves x 16 rows)
#define NSHARD_DIV 6250  // NN/8 node-range per XCD shard (fill kernel)
#define GB ((NN + RB - 1) / RB)      // 782 MFMA blocks
#define EBQ ((NE + 1023) / 1024)     // 586 edge chunks (4 edges/thread)
#define SB ((NN + 1023) / 1024)      // 49 scan blocks
#define NSH2 12500                   // nodes per gather shard (NN/4)
#define GQB2 (8 * ((NSH2 + 15) / 16))   // 6256 gather blocks (8 shards x 782)

typedef __bf16 bfrag __attribute__((ext_vector_type(8)));
typedef float  ffrag __attribute__((ext_vector_type(4)));
typedef unsigned uintv4 __attribute__((ext_vector_type(4)));   // native vec for nontemporal
typedef unsigned uintv2 __attribute__((ext_vector_type(2)));

union frag_cast { uintv4 u4; unsigned u[4]; bfrag b; };

__device__ __forceinline__ float bfbits2f(unsigned v) { return __uint_as_float(v << 16); }
__device__ __forceinline__ unsigned f2bfbits(float f) {
    unsigned u = __float_as_uint(f);
    return (u + 0x7FFFu + ((u >> 16) & 1u)) >> 16;   // RNE
}

__device__ __forceinline__ float ld_in(const void* p, int idx, int f32) {
    return f32 ? ((const float*)p)[idx]
               : bfbits2f(((const unsigned short*)p)[idx]);
}

__device__ __forceinline__ void ld_edge_nt(const int* adj, int e, int i64, int& s, int& d) {
    if (i64) {
        s = __builtin_nontemporal_load(&adj[4 * e]);
        d = __builtin_nontemporal_load(&adj[4 * e + 2]);
    } else {
        s = __builtin_nontemporal_load(&adj[2 * e]);
        d = __builtin_nontemporal_load(&adj[2 * e + 1]);
    }
}

// ---------------- prep: weight transpose + sniff + DEG zeroing ----------------
__global__ void k_prep(const unsigned* __restrict__ Ww, const unsigned* __restrict__ adjw,
                       const void* __restrict__ We, const void* __restrict__ Wu,
                       unsigned short* __restrict__ WeT, unsigned short* __restrict__ WuT,
                       int* __restrict__ flags, int* __restrict__ deg) {
    const int tid = threadIdx.x;
    if (blockIdx.x < DD) {
        __shared__ int scnt;
        if (tid == 0) scnt = 0;
        __syncthreads();
        int c = 0;
        for (int i = tid; i < 512; i += 256) {
            unsigned e = (Ww[i] >> 7) & 0xFFu;
            c += (e >= 0x60u && e <= 0x85u) ? 1 : 0;   // plausible low-half bf16?
        }
        atomicAdd(&scnt, c);
        __syncthreads();
        const int f32 = (scnt >= 256) ? 0 : 1;
        const int k = blockIdx.x;
        if (tid < DD) {
            WeT[tid * DD + k] = (unsigned short)f2bfbits(ld_in(We, k * DD + tid, f32));
        } else {
            int n = tid - DD;
            WuT[n * DD + k] = (unsigned short)f2bfbits(ld_in(Wu, k * DD + n, f32));
        }
        return;
    }
    for (int i = (blockIdx.x - DD) * 256 + tid; i < NN; i += 64 * 256) deg[i] = 0;
    if (blockIdx.x != DD) return;
    __shared__ int cnt[2];
    if (tid < 2) cnt[tid] = 0;
    __syncthreads();
    int c0 = 0, c1 = 0;
    for (int i = tid; i < 512; i += 256) {
        unsigned e = (Ww[i] >> 7) & 0xFFu;
        c0 += (e >= 0x60u && e <= 0x85u) ? 1 : 0;
        c1 += (adjw[2 * i + 1] == 0u) ? 1 : 0;          // int64 zero high words?
    }
    atomicAdd(&cnt[0], c0);
    atomicAdd(&cnt[1], c1);
    __syncthreads();
    if (tid == 0) {
        flags[0] = (cnt[0] >= 256) ? 0 : 1;   // fp32 inputs?
        flags[1] = (cnt[1] >= 256) ? 1 : 0;   // int64 adjacency?
    }
}

// ---------------- W staging: fragment-major LDS, INVERSE permutation ----------------
// LDS dst is tid-contiguous (conflict-free ds_write_b128, verified: conflicts -> 0);
// the permuted GLOBAL read is L2-hot (32 KB reused by every block).
__device__ __forceinline__ void stage_w(const uintv4* __restrict__ WTg, uintv4* sW, int tid) {
#pragma unroll
    for (int k = 0; k < 8; k++) {
        int d = k * 256 + tid;
        int m = d & 15, rest = d >> 4;
        int quad = rest & 3, ks = (rest >> 2) & 3, ct = rest >> 4;
        sW[d] = WTg[(ct * 16 + m) * 16 + (ks * 4 + quad)];
    }
}

// ---------------- MFMA core: A from registers, B fragment-major from LDS ----------
__device__ __forceinline__ void mfma_rows(const bfrag af[4], const bfrag* sW,
                                          int m, int quad, ffrag acc[8]) {
#pragma unroll
    for (int ks = 0; ks < 4; ks++) {
#pragma unroll
        for (int ct = 0; ct < 8; ct++) {
            bfrag bf_ = sW[((ct * 4 + ks) * 4 + quad) * 16 + m];
            acc[ct] = __builtin_amdgcn_mfma_f32_16x16x32_bf16(af[ks], bf_, acc[ct], 0, 0, 0);
        }
    }
}

// H layout between GEMMs: 2 HALF-ROW PLANES H2[plane][node][64cols] (128B/node/plane)
// -> every gather neighbor-read is ONE fully-used 128B L2 line request
//    (was: 8 planes x 32B sectors = 4x the requests at 1/4 line efficiency).
__device__ __forceinline__ void st_h2(unsigned short* __restrict__ Hout,
                                      int ct, int m, int orow, float z) {
    Hout[(size_t)(ct >> 2) * (NN * 64) + (size_t)orow * 64 + (ct & 3) * 16 + m] =
        (unsigned short)f2bfbits(z);
}

// ---------------- fused: emb GEMM (blocks < GB) || degree+slot atomics (rest) ------
__launch_bounds__(256, 5)
__global__ void k_main1(const void* __restrict__ Xp, const unsigned short* __restrict__ WTg,
                        const void* __restrict__ Bp, unsigned short* __restrict__ Hout,
                        const int* __restrict__ flags, const int* __restrict__ adj,
                        int* __restrict__ deg, uintv2* __restrict__ edg) {
    __shared__ __align__(16) unsigned short sWT[DD * DD];  // 32 KB
    const int tid = threadIdx.x;
    if (blockIdx.x >= GB) {
        // -------- edge path: degree count with returning atomics --------
        const int bb = blockIdx.x - GB;
        const int i64 = flags[1];
#pragma unroll
        for (int k = 0; k < 4; k++) {
            const int e = bb * 1024 + k * 256 + tid;
            if (e < NE) {
                int s, d;
                ld_edge_nt(adj, e, i64, s, d);
                uintv2 out;
                if ((unsigned)s < NN && (unsigned)d < NN) {
                    int ks = atomicAdd(&deg[s], 1);
                    int kd = atomicAdd(&deg[d], 1);
                    out[0] = (unsigned)s | ((unsigned)d << 16);
                    out[1] = (unsigned)ks | ((unsigned)kd << 16);  // max deg ~60 << 65536
                } else {
                    out[0] = 0xFFFFFFFFu;  // sentinel: skip in fill
                    out[1] = 0;
                }
                __builtin_nontemporal_store(out, &edg[e]);
            }
        }
        return;
    }
    // -------- emb path: h0 = relu(X @ W_emb + b) -> bf16 half-row planes --------
    const int wave = tid >> 6;
    const int lane = tid & 63;
    const int f32  = flags[0];
    const int m    = lane & 15;
    const int quad = lane >> 4;
    const int rowbase = blockIdx.x * RB + wave * 16;
    const int row  = rowbase + m;
    const int rc   = (row < NN) ? row : (NN - 1);   // clamp for load; stores guarded

    stage_w((const uintv4*)WTg, (uintv4*)sWT, tid);

    bfrag af[4];
    if (f32) {
        const float4* Xf = (const float4*)Xp;
#pragma unroll
        for (int ks = 0; ks < 4; ks++) {
            const int k0 = ks * 32 + quad * 8;
            float4 a0 = Xf[rc * 32 + (k0 >> 2)];
            float4 a1 = Xf[rc * 32 + (k0 >> 2) + 1];
            frag_cast fc;
            fc.u[0] = f2bfbits(a0.x) | (f2bfbits(a0.y) << 16);
            fc.u[1] = f2bfbits(a0.z) | (f2bfbits(a0.w) << 16);
            fc.u[2] = f2bfbits(a1.x) | (f2bfbits(a1.y) << 16);
            fc.u[3] = f2bfbits(a1.z) | (f2bfbits(a1.w) << 16);
            af[ks] = fc.b;
        }
    } else {
        const uintv4* Xv = (const uintv4*)Xp;
#pragma unroll
        for (int ks = 0; ks < 4; ks++) {
            const int k0 = ks * 32 + quad * 8;
            frag_cast fc;
            fc.u4 = Xv[rc * 16 + (k0 >> 3)];
            af[ks] = fc.b;
        }
    }
    __syncthreads();

    ffrag acc[8];
#pragma unroll
    for (int i = 0; i < 8; i++) acc[i] = (ffrag)(0.0f);
    mfma_rows(af, (const bfrag*)sWT, m, quad, acc);

#pragma unroll
    for (int ct = 0; ct < 8; ct++) {
        int col = ct * 16 + m;
        float bb = ld_in(Bp, col, f32);
#pragma unroll
        for (int reg = 0; reg < 4; reg++) {
            int orow = rowbase + quad * 4 + reg;
            if (orow < NN) {
                float z = fmaxf(acc[ct][reg] + bb, 0.0f);
                st_h2(Hout, ct, m, orow, z);
            }
        }
    }
}

// ---------------- hierarchical scan (wave-shuffle, 2 barriers) ----------------
__global__ void k_scan1(const int* __restrict__ deg, int* __restrict__ rows,
                        int* __restrict__ sums) {
    __shared__ int wsum[16];
    __shared__ int woff[16];
    const int tid  = threadIdx.x;
    const int wid  = tid >> 6;
    const int lane = tid & 63;
    const int i = blockIdx.x * 1024 + tid;
    int x = (i < NN) ? deg[i] : 0;
#pragma unroll
    for (int off = 1; off < 64; off <<= 1) {
        int y = __shfl_up(x, off, 64);
        if (lane >= off) x += y;
    }
    if (lane == 63) wsum[wid] = x;
    __syncthreads();
    if (wid == 0) {
        int s  = (lane < 16) ? wsum[lane] : 0;
        int xs = s;
#pragma unroll
        for (int off = 1; off < 16; off <<= 1) {
            int y = __shfl_up(xs, off, 64);
            if (lane >= off) xs += y;
        }
        if (lane < 16) woff[lane] = xs - s;
        if (lane == 15) sums[blockIdx.x] = xs;
    }
    __syncthreads();
    if (i < NN) rows[i + 1] = x + woff[wid];
}

__global__ void k_scan2(int* __restrict__ sums, int nb) {
    int t = threadIdx.x;                 // one wave of 64
    int v = (t < nb) ? sums[t] : 0;
    int x = v;
    for (int off = 1; off < 64; off <<= 1) {
        int y = __shfl_up(x, off, 64);
        if (t >= off) x += y;
    }
    if (t < nb) sums[t] = x - v;         // exclusive
}

__global__ void k_scan3(const int* __restrict__ sums, int* __restrict__ rows) {
    int i = blockIdx.x * 1024 + threadIdx.x;
    if (i < NN) {
        rows[i + 1] += sums[blockIdx.x];
        if (i == 0) rows[0] = 0;
    }
}

// ---------------- atomic-free XCD-sharded fill: slot = rows[s] + precomputed ks ----
__launch_bounds__(256)
__global__ void k_fill2(const uintv2* __restrict__ edg, const int* __restrict__ rows,
                        unsigned short* __restrict__ nbr) {
    const int shard = blockIdx.x & 7;
    const int bb = blockIdx.x >> 3;
#pragma unroll
    for (int k = 0; k < 4; k++) {
        const int e = bb * 1024 + k * 256 + threadIdx.x;
        if (e >= NE) continue;
        uintv2 v = __builtin_nontemporal_load(&edg[e]);
        if (v[0] == 0xFFFFFFFFu) continue;
        const int s = v[0] & 0xFFFFu, d = v[0] >> 16;
        if (s / NSHARD_DIV == shard) nbr[rows[s] + (v[1] & 0xFFFFu)] = (unsigned short)d;
        if (d / NSHARD_DIV == shard) nbr[rows[d] + (v[1] >> 16)]    = (unsigned short)s;
    }
}

// ---------------- full-line gather: shard = (plane, node-quadrant) ----------------
// H2[2][NN][64cols]: a neighbor read is 16 lanes x 8B = ONE fully-used 128B line
// request (4x fewer L2/L3 requests than the 32B-sector layout, 100% line use).
// Shards 0-3: plane 0 x node quadrant; 4-7: plane 1. Each XCD streams one 6.4 MB
// plane (partially L2-resident; misses pull FULL lines from L3). nbr loads are
// plain scalar (16-lane broadcast, L1-served; NT hurt: R4. shfl-coop hurt: R5).
__launch_bounds__(256)
__global__ void k_gath4(const unsigned* __restrict__ Hp, const int* __restrict__ rows,
                        const unsigned short* __restrict__ nbr,
                        unsigned* __restrict__ XB32) {
    const int shard = blockIdx.x & 7;
    const int plane = shard >> 2;
    const int qr    = shard & 3;
    const int nrel  = (blockIdx.x >> 3) * 16 + (threadIdx.x >> 4);
    const int cs2   = threadIdx.x & 15;
    const int nid   = qr * NSH2 + ((nrel < NSH2) ? nrel : (NSH2 - 1));
    const uintv2* Pv = (const uintv2*)Hp + (size_t)plane * (NN * 16);
    const int st = rows[nid], en = rows[nid + 1];
    uintv2 sv = Pv[nid * 16 + cs2];                    // self term
    float a0 = bfbits2f(sv[0] & 0xFFFFu), a1 = bfbits2f(sv[0] >> 16);
    float a2 = bfbits2f(sv[1] & 0xFFFFu), a3 = bfbits2f(sv[1] >> 16);
    int j = st;
    for (; j + 8 <= en; j += 8) {                      // 8 line-loads in flight
        int n[8];
#pragma unroll
        for (int t = 0; t < 8; t++) n[t] = nbr[j + t];
        uintv2 v[8];
#pragma unroll
        for (int t = 0; t < 8; t++) v[t] = Pv[n[t] * 16 + cs2];
#pragma unroll
        for (int t = 0; t < 8; t++) {
            a0 += bfbits2f(v[t][0] & 0xFFFFu);
            a1 += bfbits2f(v[t][0] >> 16);
            a2 += bfbits2f(v[t][1] & 0xFFFFu);
            a3 += bfbits2f(v[t][1] >> 16);
        }
    }
    for (; j < en; ++j) {
        uintv2 v = Pv[(int)nbr[j] * 16 + cs2];
        a0 += bfbits2f(v[0] & 0xFFFFu);
        a1 += bfbits2f(v[0] >> 16);
        a2 += bfbits2f(v[1] & 0xFFFFu);
        a3 += bfbits2f(v[1] >> 16);
    }
    const float inv = 1.0f / (float)(en - st + 1);
    if (nrel < NSH2) {
        uintv2 pk;
        pk[0] = f2bfbits(a0 * inv) | (f2bfbits(a1 * inv) << 16);
        pk[1] = f2bfbits(a2 * inv) | (f2bfbits(a3 * inv) << 16);
        // dwords [plane*32, plane*32+32) of row nid -> assembles row-major XB
        __builtin_nontemporal_store(pk, (uintv2*)XB32 + (size_t)nid * 32 + plane * 16 + cs2);
    }
}

// ---------------- GEMM 2: h_new = sigmoid(XB @ W_upd + b) ----------------
// !last: write half-row planes (feeds next gather). last: row-major f32 to d_out.
__launch_bounds__(256, 5)
__global__ void k_gemmB(const unsigned short* __restrict__ XB,
                        const unsigned short* __restrict__ WTg, const void* __restrict__ Bp,
                        unsigned short* __restrict__ HoutBf, float* __restrict__ HoutF,
                        const int* __restrict__ flags, int last) {
    __shared__ __align__(16) unsigned short sWT[DD * DD];  // 32 KB
    const int tid  = threadIdx.x;
    const int wave = tid >> 6;
    const int lane = tid & 63;
    const int f32  = flags[0];
    const int m    = lane & 15;
    const int quad = lane >> 4;
    const int rowbase = blockIdx.x * RB + wave * 16;
    const int row  = rowbase + m;

    stage_w((const uintv4*)WTg, (uintv4*)sWT, tid);

    bfrag af[4];
    const uintv4* Xv = (const uintv4*)XB;
#pragma unroll
    for (int ks = 0; ks < 4; ks++) {
        const int k0 = ks * 32 + quad * 8;
        frag_cast fc;
        fc.u4 = __builtin_nontemporal_load(&Xv[row * 16 + (k0 >> 3)]);  // single-use stream
        af[ks] = fc.b;
    }
    __syncthreads();

    ffrag acc[8];
#pragma unroll
    for (int i = 0; i < 8; i++) acc[i] = (ffrag)(0.0f);
    mfma_rows(af, (const bfrag*)sWT, m, quad, acc);

#pragma unroll
    for (int ct = 0; ct < 8; ct++) {
        int col = ct * 16 + m;
        float bb = ld_in(Bp, col, f32);
#pragma unroll
        for (int reg = 0; reg < 4; reg++) {
            int orow = rowbase + quad * 4 + reg;
            if (orow < NN) {
                float s = 1.0f / (1.0f + __expf(-(acc[ct][reg] + bb)));
                if (!last) {
                    st_h2(HoutBf, ct, m, orow, s);
                } else if (f32) {
                    HoutF[orow * DD + col] = s;
                } else {
                    ((unsigned short*)HoutF)[orow * DD + col] = (unsigned short)f2bfbits(s);
                }
            }
        }
    }
}

extern "C" void kernel_launch(void* const* d_in, const int* in_sizes, int n_in,
                              void* d_out, int out_size, void* d_ws, size_t ws_size,
                              hipStream_t stream) {
    const void* X  = d_in[0];
    const void* We = d_in[1];
    const void* be = d_in[2];
    const void* Wu = d_in[3];
    const void* bu = d_in[4];
    const int* adj = (const int*)d_in[5];

    // ws: FLAGS | ROWS | SUMS | NBR(2.4M) | WeT | WuT | HW(12.8M + 16K slack)
    // HW overlays EDG2(4.8M) + DEG(200K): both dead after fill2/scan1, before it0
    // writes HW. Total ~15.5 MB.
    char* p = (char*)d_ws;
    int* FLAGS = (int*)p;                       p += 256;
    int* ROWS  = (int*)p;                       p += ((NN + 1) * 4 + 252) / 256 * 256;
    int* SUMS  = (int*)p;                       p += 256;
    unsigned short* NBR = (unsigned short*)p;   p += (size_t)2 * NE * 2;
    unsigned short* WeT = (unsigned short*)p;   p += DD * DD * 2;
    unsigned short* WuT = (unsigned short*)p;   p += DD * DD * 2;
    unsigned short* HW  = (unsigned short*)p;   // 12.8 MB + slack (gemmB over-read)
    uintv2* EDG2 = (uintv2*)p;                  // overlays HW[0 .. 4.8M)
    int* DEG = (int*)(p + (size_t)NE * 8);      // overlays HW[4.8M .. 5.0M)

    // h planes live in d_out's upper half (bytes 12.8M..25.6M); dead before the
    // final row-major f32 write (gather consumes them first, stream-ordered).
    unsigned short* HA = (unsigned short*)d_out + (size_t)NN * DD;

    k_prep<<<DD + 64, 256, 0, stream>>>((const unsigned*)We, (const unsigned*)adj,
                                        We, Wu, WeT, WuT, FLAGS, DEG);
    k_main1<<<GB + EBQ, 256, 0, stream>>>(X, WeT, be, HA, FLAGS, adj, DEG, EDG2);
    k_scan1<<<SB, 1024, 0, stream>>>(DEG, ROWS, SUMS);
    k_scan2<<<1, 64, 0, stream>>>(SUMS, SB);
    k_scan3<<<SB, 1024, 0, stream>>>(SUMS, ROWS);
    k_fill2<<<8 * EBQ, 256, 0, stream>>>(EDG2, ROWS, NBR);

    for (int it = 0; it < 3; ++it) {
        int last = (it == 2);
        k_gath4<<<GQB2, 256, 0, stream>>>((const unsigned*)HA, ROWS, NBR, (unsigned*)HW);
        k_gemmB<<<GB, 256, 0, stream>>>(HW, WuT, bu, HA, (float*)d_out, FLAGS, last);
    }
}